// Round 19
// baseline (24.401 us; speedup 1.0000x reference)
//
#include <hip/hip_runtime.h>
#include <math.h>

#define N_ROWS 1024
#define RANK   8
#define M_COLS 4096

#define R_ROWS   2      // n-rows per thread
#define T_PTS    2      // direct points per thread in [1,2048], stride 1024
#define M_STRIDE 1024

// Static device scratch (fully overwritten every call before read).
__device__ float2 g_Hft[RANK * M_COLS];        // FFT of softplus(H), 256 KB
__device__ float4 g_Tab4[N_ROWS * RANK];       // {vr, vi, wcr, wci}, 128 KB
__device__ float2 g_Tab2[N_ROWS * RANK];       // {ws, tau}, 64 KB
__device__ float2 g_T1[N_ROWS * RANK * 64];    // e^{+2pi i tau l/4096}, l<64, 4 MB
__device__ float2 g_T2[N_ROWS * RANK * 16];    // e^{+2pi i tau (1+64qq)/4096}, 1 MB

// fast softplus: 2 trans + ~4 VALU. exact for x>20; inputs are ~N(0,1).
__device__ __forceinline__ float softplus_f(float x) {
    float t = __expf(x);
    float r = 0.69314718056f * __log2f(1.0f + t);
    return (x > 20.0f) ? x : r;
}
// hw trig: v_sin/v_cos compute sin/cos(2*pi*x), x in revolutions.
__device__ __forceinline__ float sin_rev(float x) { return __builtin_amdgcn_sinf(x); }
__device__ __forceinline__ float cos_rev(float x) { return __builtin_amdgcn_cosf(x); }
__device__ __forceinline__ float fract_f(float x) { return __builtin_amdgcn_fractf(x); }
// block-uniform float -> SGPR
__device__ __forceinline__ float rfl(float x) {
    return __int_as_float(__builtin_amdgcn_readfirstlane(__float_as_int(x)));
}

// ---------------------------------------------------------------------------
// Phase-1 kernel. Blocks 0..127: widened fft (R18-proven, 512 thr, split-sum);
// blocks 0..15 also fill Tab4/Tab2. Blocks 128..1151: g_T1 (1 entry/thread).
// Blocks 1152..1407: g_T2. Table blocks run on CUs the fft leaves idle.
// ---------------------------------------------------------------------------
__global__ void fft_fused(const float* __restrict__ H,
                          const float* __restrict__ W,
                          const float* __restrict__ tau) {
    const int tid = threadIdx.x;          // 0..511
    const int b   = blockIdx.x;

    if (b >= 128) {                       // ---- table generation ----
        if (b < 1152) {                   // g_T1: idx = nd*64 + l
            int idx = (b - 128) * 512 + tid;
            int nd  = idx >> 6;
            int l   = idx & 63;
            float tv  = tau[nd];          // 64 lanes share -> broadcast
            float rev = fract_f(tv * ((float)l * (1.0f / (float)M_COLS)));
            g_T1[idx] = make_float2(cos_rev(rev), sin_rev(rev));
        } else {                          // g_T2: idx = nd*16 + qq
            int idx = (b - 1152) * 512 + tid;
            int nd  = idx >> 4;
            int qq  = idx & 15;
            float tv  = tau[nd];
            float rev = fract_f(tv * ((float)(1 + 64 * qq) * (1.0f / (float)M_COLS)));
            g_T2[idx] = make_float2(cos_rev(rev), sin_rev(rev));
        }
        return;
    }

    __shared__ float  sHs[M_COLS];        // 16 KB
    __shared__ float2 sY [4 * 64];        // stage-A combined, [m0j][k0], 2 KB
    __shared__ float2 sP [512];           // partials (A and B), 4 KB

    const int d   = b >> 4;
    const int m0b = (b & 15) << 2;

    if (b < 16) {                         // Tab4/Tab2 side-job: 16 x 512 = 8192
        int t = b * 512 + tid;
        float w  = softplus_f(W[t]);
        float tv = tau[t];
        float rv = fract_f(tv * ((float)M_STRIDE / (float)M_COLS));  // tv/4
        float4 t4;
        t4.x = cos_rev(rv);               // step = e^{+i 2pi tau*1024/M}
        t4.y = sin_rev(rv);
        float rc = fract_f(-tv);          // e^{-2pi i tau}
        t4.z = w * cos_rev(rc);           // wcr
        t4.w = w * sin_rev(rc);           // wci
        g_Tab4[t] = t4;
        g_Tab2[t] = make_float2(w, tv);
    }

    const float4* Hrow4 = (const float4*)(H + d * M_COLS);
    #pragma unroll
    for (int p = 0; p < 2; ++p) {
        int i = p * 512 + tid;
        float4 h4 = Hrow4[i];
        sHs[i*4+0] = softplus_f(h4.x);
        sHs[i*4+1] = softplus_f(h4.y);
        sHs[i*4+2] = softplus_f(h4.z);
        sHs[i*4+3] = softplus_f(h4.w);
    }
    __syncthreads();

    {   // stage A partial: tid = half*256 + m0j*64 + k0
        int k0   = tid & 63;
        int m0j  = (tid >> 6) & 3;
        int half = tid >> 8;
        int m0   = m0b + m0j;
        float mrev = (float)m0 * (1.0f / 64.0f);
        float rr =  cos_rev(mrev);
        float ri = -sin_rev(mrev);        // rot = e^{-2pi i m0/64}
        float twr = ((half & m0) & 1) ? -1.0f : 1.0f;   // exact init
        float twi = 0.0f;
        float ar = 0.0f, ai = 0.0f;
        int base = half << 5;
        #pragma unroll
        for (int k = 0; k < 32; ++k) {
            float v = sHs[((base + k) << 6) + k0];
            ar = fmaf(v, twr, ar);
            ai = fmaf(v, twi, ai);
            float nr = fmaf(twr, rr, -(twi * ri));
            twi      = fmaf(twr, ri,   twi * rr);
            twr = nr;
        }
        sP[tid] = make_float2(ar, ai);
    }
    __syncthreads();
    if (tid < 256) {
        float2 a = sP[tid], c = sP[256 + tid];
        sY[tid] = make_float2(a.x + c.x, a.y + c.y);
    }
    __syncthreads();

    {   // stage B partial: tid = half*256 + m0j*64 + m1
        int m1   = tid & 63;
        int m0j  = (tid >> 6) & 3;
        int half = tid >> 8;
        int m    = (m1 << 6) + m0b + m0j;
        float mrev = (float)m * (1.0f / 4096.0f);
        float rr =  cos_rev(mrev);
        float ri = -sin_rev(mrev);        // rot = e^{-2pi i m/4096}
        float irev = (float)((m * (half << 5)) & 4095) * (1.0f / 4096.0f);
        float twr =  cos_rev(irev);
        float twi = -sin_rev(irev);
        float ar = 0.0f, ai = 0.0f;
        int base = half << 5;
        #pragma unroll
        for (int k = 0; k < 32; ++k) {
            float2 y = sY[(m0j << 6) + base + k];
            ar = fmaf(y.x, twr, fmaf(-y.y, twi, ar));
            ai = fmaf(y.x, twi, fmaf( y.y, twr, ai));
            float nr = fmaf(twr, rr, -(twi * ri));
            twi      = fmaf(twr, ri,   twi * rr);
            twr = nr;
        }
        sP[tid] = make_float2(ar, ai);
    }
    __syncthreads();
    if (tid < 256) {
        int m1 = tid & 63, m0j = tid >> 6;
        float2 a = sP[tid], c = sP[256 + tid];
        int m = (m1 << 6) + m0b + m0j;
        g_Hft[d * M_COLS + m] = make_float2(a.x + c.x, a.y + c.y);
    }
}

// ---------------------------------------------------------------------------
// Main: ZERO transcendentals. u = T2[nd,qq]·T1[nd,l] from LDS-staged tables
// (staged once per block, coalesced). Mirror math R13-verbatim:
//   zr = ur*hr + ui*hi ; zi = ur*hi - ui*hr
//   Re V[n,m]      += ws * zr
//   Re V[n,4096-m] += wcr*zr + wci*zi
// grid (4,512) = 2048 blocks = 8 waves/SIMD; LDS 10.5 KB/block.
// ---------------------------------------------------------------------------
__global__ void shiftnmf_main(float* __restrict__ out) {
    __shared__ float2 sT1[2 * RANK * 64];   // [r][d][l], 8 KB
    __shared__ float2 sT2[2 * RANK * 16];   // [r][d][qq], 2 KB

    const int tid = threadIdx.x;
    const int bx  = blockIdx.x;
    const int m0  = bx * 256 + tid;       // 0..1023 ; m_j = 1 + m0 + j*1024
    const int n0  = blockIdx.y * R_ROWS;
    const int l   = tid & 63;
    const int qq  = (bx << 2) + (tid >> 6);   // wave-uniform, in [0,16)

    // stage tables: T1 rows n0,n0+1 are contiguous (1024 entries from n0*512)
    {
        const float2* src = g_T1 + n0 * (RANK * 64);
        #pragma unroll
        for (int p = 0; p < 4; ++p)
            sT1[p * 256 + tid] = src[p * 256 + tid];
        sT2[tid] = g_T2[n0 * (RANK * 16) + tid];   // 256 entries, 1/thread
    }
    __syncthreads();

    float accm[R_ROWS][T_PTS];            // direct outputs, m
    float accx[R_ROWS][T_PTS];            // mirror outputs, 4096-m
    #pragma unroll
    for (int r = 0; r < R_ROWS; ++r)
        #pragma unroll
        for (int j = 0; j < T_PTS; ++j) { accm[r][j] = 0.0f; accx[r][j] = 0.0f; }

    #pragma unroll
    for (int d = 0; d < RANK; ++d) {
        float ur[R_ROWS], ui[R_ROWS];                 // unit phasor (per-lane)
        float vr[R_ROWS], vi[R_ROWS];                 // step (SGPR)
        float ws[R_ROWS], wcr[R_ROWS], wci[R_ROWS];   // weights (SGPR)
        #pragma unroll
        for (int r = 0; r < R_ROWS; ++r) {
            int nd = (n0 + r) * RANK + d;
            float4 t4 = g_Tab4[nd];                   // block-uniform
            vr[r]  = rfl(t4.x);  vi[r]  = rfl(t4.y);
            wcr[r] = rfl(t4.z);  wci[r] = rfl(t4.w);
            ws[r]  = rfl(g_Tab2[nd].x);
            float2 u0 = sT2[(r * RANK + d) * 16 + qq];    // wave-uniform LDS
            float u0r = rfl(u0.x), u0i = rfl(u0.y);
            float2 t1 = sT1[(r * RANK + d) * 64 + l];     // per-lane LDS, 2-way
            ur[r] = fmaf(u0r, t1.x, -(u0i * t1.y));       // u = U0*T1
            ui[r] = fmaf(u0r, t1.y,   u0i * t1.x);
        }

        const float2* hp = g_Hft + d * M_COLS + 1 + m0;
        #pragma unroll
        for (int j = 0; j < T_PTS; ++j) {
            float2 h = hp[j * M_STRIDE];              // coalesced, L2-resident
            #pragma unroll
            for (int r = 0; r < R_ROWS; ++r) {
                float t1v = ui[r] * h.y;
                float zr = fmaf(ur[r], h.x, t1v);     // Re(conj(u)h)
                float t2v = ui[r] * h.x;
                float zi = fmaf(ur[r], h.y, -t2v);    // Im(conj(u)h)
                accm[r][j] = fmaf(ws[r],  zr, accm[r][j]);
                accx[r][j] = fmaf(wcr[r], zr, fmaf(wci[r], zi, accx[r][j]));
                if (j < T_PTS - 1) {                  // u *= v (skip dead last)
                    float nr = fmaf(ur[r], vr[r], -(ui[r] * vi[r]));
                    ui[r]    = fmaf(ur[r], vi[r],   ui[r] * vr[r]);
                    ur[r]    = nr;
                }
            }
        }
    }

    #pragma unroll
    for (int r = 0; r < R_ROWS; ++r) {
        float* op = out + (n0 + r) * M_COLS;
        #pragma unroll
        for (int j = 0; j < T_PTS; ++j)
            op[1 + m0 + j * M_STRIDE] = accm[r][j];    // m in [1,2048]
        #pragma unroll
        for (int j = 0; j < T_PTS; ++j)
            op[4095 - m0 - j * M_STRIDE] = accx[r][j]; // 4096-m in [2048,4095]
    }

    if (bx == 0 && tid == 0) {                        // column 0, direct
        #pragma unroll
        for (int r = 0; r < R_ROWS; ++r) {
            int n = n0 + r;
            float a = 0.0f;
            #pragma unroll
            for (int d = 0; d < RANK; ++d)
                a = fmaf(g_Tab2[n * RANK + d].x, g_Hft[d * M_COLS].x, a);
            out[n * M_COLS] = a;
        }
    }
}

extern "C" void kernel_launch(void* const* d_in, const int* in_sizes, int n_in,
                              void* d_out, int out_size, void* d_ws, size_t ws_size,
                              hipStream_t stream) {
    const float* W   = (const float*)d_in[0];   // [1024, 8]
    const float* H   = (const float*)d_in[1];   // [8, 4096]
    const float* tau = (const float*)d_in[2];   // [1024, 8]

    // 128 fft blocks + 1024 T1 blocks + 256 T2 blocks, all 512-thread
    fft_fused<<<dim3(1408), dim3(512), 0, stream>>>(H, W, tau);

    dim3 grid(M_COLS / 2 / (256 * T_PTS), N_ROWS / R_ROWS);  // (4, 512)
    shiftnmf_main<<<grid, dim3(256), 0, stream>>>((float*)d_out);
}

// Round 20
// 19.109 us; speedup vs baseline: 1.2769x; 1.2769x over previous
//
#include <hip/hip_runtime.h>
#include <math.h>

#define N_ROWS 1024
#define RANK   8
#define M_COLS 4096

#define R_ROWS   2      // n-rows per thread
#define T_PTS    4      // direct points per thread in [1,2048], stride 512
#define M_STRIDE 512

// Static device scratch (fully overwritten every call before read).
__device__ float2 g_Hft[RANK * M_COLS];    // full FFT of softplus(H), 256 KB
__device__ float4 g_Tab4[N_ROWS * RANK];   // {vr, vi, wcr, wci} per (n,d), 128 KB
__device__ float2 g_Tab2[N_ROWS * RANK];   // {ws, tau}          per (n,d),  64 KB

// fast softplus: 2 trans + ~4 VALU. exact for x>20; inputs are ~N(0,1).
__device__ __forceinline__ float softplus_f(float x) {
    float t = __expf(x);
    float r = 0.69314718056f * __log2f(1.0f + t);
    return (x > 20.0f) ? x : r;
}
// hw trig: v_sin/v_cos compute sin/cos(2*pi*x), x in revolutions.
__device__ __forceinline__ float sin_rev(float x) { return __builtin_amdgcn_sinf(x); }
__device__ __forceinline__ float cos_rev(float x) { return __builtin_amdgcn_cosf(x); }
__device__ __forceinline__ float fract_f(float x) { return __builtin_amdgcn_fractf(x); }
// block-uniform float -> SGPR
__device__ __forceinline__ float rfl(float x) {
    return __int_as_float(__builtin_amdgcn_readfirstlane(__float_as_int(x)));
}

// ---------------------------------------------------------------------------
// Widened fused FFT (R18-proven, unchanged): 128 blocks x 512 threads,
// split-sum stages, blocks 0..15 fill Tab4/Tab2.
// ---------------------------------------------------------------------------
__global__ void fft_fused(const float* __restrict__ H,
                          const float* __restrict__ W,
                          const float* __restrict__ tau) {
    __shared__ float  sHs[M_COLS];        // 16 KB
    __shared__ float2 sY [4 * 64];        // stage-A combined, [m0j][k0], 2 KB
    __shared__ float2 sP [512];           // partials (A and B), 4 KB

    const int tid = threadIdx.x;          // 0..511
    const int b   = blockIdx.x;           // 0..127
    const int d   = b >> 4;
    const int m0b = (b & 15) << 2;

    if (b < 16) {                         // table side-job: 16 x 512 = 8192
        int t = b * 512 + tid;
        float w  = softplus_f(W[t]);
        float tv = tau[t];
        float rv = fract_f(tv * ((float)M_STRIDE / (float)M_COLS));  // tv/8
        float4 t4;
        t4.x = cos_rev(rv);               // step = e^{+i 2pi tau*512/M}
        t4.y = sin_rev(rv);
        float rc = fract_f(-tv);          // e^{-2pi i tau}
        t4.z = w * cos_rev(rc);           // wcr
        t4.w = w * sin_rev(rc);           // wci
        g_Tab4[t] = t4;
        g_Tab2[t] = make_float2(w, tv);
    }

    const float4* Hrow4 = (const float4*)(H + d * M_COLS);
    #pragma unroll
    for (int p = 0; p < 2; ++p) {
        int i = p * 512 + tid;
        float4 h4 = Hrow4[i];
        sHs[i*4+0] = softplus_f(h4.x);
        sHs[i*4+1] = softplus_f(h4.y);
        sHs[i*4+2] = softplus_f(h4.z);
        sHs[i*4+3] = softplus_f(h4.w);
    }
    __syncthreads();

    {   // stage A partial: tid = half*256 + m0j*64 + k0
        int k0   = tid & 63;
        int m0j  = (tid >> 6) & 3;
        int half = tid >> 8;
        int m0   = m0b + m0j;
        float mrev = (float)m0 * (1.0f / 64.0f);
        float rr =  cos_rev(mrev);
        float ri = -sin_rev(mrev);        // rot = e^{-2pi i m0/64}
        float twr = ((half & m0) & 1) ? -1.0f : 1.0f;   // exact init
        float twi = 0.0f;
        float ar = 0.0f, ai = 0.0f;
        int base = half << 5;
        #pragma unroll
        for (int k = 0; k < 32; ++k) {
            float v = sHs[((base + k) << 6) + k0];
            ar = fmaf(v, twr, ar);
            ai = fmaf(v, twi, ai);
            float nr = fmaf(twr, rr, -(twi * ri));
            twi      = fmaf(twr, ri,   twi * rr);
            twr = nr;
        }
        sP[tid] = make_float2(ar, ai);
    }
    __syncthreads();
    if (tid < 256) {
        float2 a = sP[tid], c = sP[256 + tid];
        sY[tid] = make_float2(a.x + c.x, a.y + c.y);
    }
    __syncthreads();

    {   // stage B partial: tid = half*256 + m0j*64 + m1
        int m1   = tid & 63;
        int m0j  = (tid >> 6) & 3;
        int half = tid >> 8;
        int m    = (m1 << 6) + m0b + m0j;
        float mrev = (float)m * (1.0f / 4096.0f);
        float rr =  cos_rev(mrev);
        float ri = -sin_rev(mrev);        // rot = e^{-2pi i m/4096}
        float irev = (float)((m * (half << 5)) & 4095) * (1.0f / 4096.0f);
        float twr =  cos_rev(irev);
        float twi = -sin_rev(irev);
        float ar = 0.0f, ai = 0.0f;
        int base = half << 5;
        #pragma unroll
        for (int k = 0; k < 32; ++k) {
            float2 y = sY[(m0j << 6) + base + k];
            ar = fmaf(y.x, twr, fmaf(-y.y, twi, ar));
            ai = fmaf(y.x, twi, fmaf( y.y, twr, ai));
            float nr = fmaf(twr, rr, -(twi * ri));
            twi      = fmaf(twr, ri,   twi * rr);
            twr = nr;
        }
        sP[tid] = make_float2(ar, ai);
    }
    __syncthreads();
    if (tid < 256) {
        int m1 = tid & 63, m0j = tid >> 6;
        float2 a = sP[tid], c = sP[256 + tid];
        int m = (m1 << 6) + m0b + m0j;
        g_Hft[d * M_COLS + m] = make_float2(a.x + c.x, a.y + c.y);
    }
}

// ---------------------------------------------------------------------------
// Main (R13/R18 math, single change: T_PTS=4, stride 512 — setup trig
// amortized over 16 outputs/thread instead of 8).
// For m = 1+m0+j*512:  u = e^{+i 2pi tau m/M}
//   zr = ur*hr + ui*hi ; zi = ur*hi - ui*hr
//   Re V[n,m]      += ws * zr
//   Re V[n,4096-m] += wcr*zr + wci*zi      (Hermitian mirror)
// grid (2,512) = 1024 blocks = 4 waves/SIMD; est. ~52 live VGPRs.
// ---------------------------------------------------------------------------
__global__ void shiftnmf_main(float* __restrict__ out) {
    int tid = threadIdx.x;
    int m0  = blockIdx.x * 256 + tid;     // 0..511 ; m_j = 1 + m0 + j*512
    int n0  = blockIdx.y * R_ROWS;

    float fm0 = (float)(1 + m0) * (1.0f / (float)M_COLS);

    float accm[R_ROWS][T_PTS];            // direct outputs, m
    float accx[R_ROWS][T_PTS];            // mirror outputs, 4096-m
    #pragma unroll
    for (int r = 0; r < R_ROWS; ++r)
        #pragma unroll
        for (int j = 0; j < T_PTS; ++j) { accm[r][j] = 0.0f; accx[r][j] = 0.0f; }

    #pragma unroll
    for (int d = 0; d < RANK; ++d) {
        float ur[R_ROWS], ui[R_ROWS];                 // unit phasor (per-lane)
        float vr[R_ROWS], vi[R_ROWS];                 // step (SGPR)
        float ws[R_ROWS], wcr[R_ROWS], wci[R_ROWS];   // weights (SGPR)
        #pragma unroll
        for (int r = 0; r < R_ROWS; ++r) {
            int nd = (n0 + r) * RANK + d;
            float4 t4 = g_Tab4[nd];                   // block-uniform
            vr[r]  = rfl(t4.x);  vi[r]  = rfl(t4.y);
            wcr[r] = rfl(t4.z);  wci[r] = rfl(t4.w);
            ws[r]  = rfl(g_Tab2[nd].x);
            float tv = rfl(g_Tab2[nd].y);
            float r0 = fract_f(tv * fm0);             // only per-thread trig
            ur[r] = cos_rev(r0);                      // u = e^{+i 2pi tau m_0/M}
            ui[r] = sin_rev(r0);
        }

        const float2* hp = g_Hft + d * M_COLS + 1 + m0;
        #pragma unroll
        for (int j = 0; j < T_PTS; ++j) {
            float2 h = hp[j * M_STRIDE];              // coalesced, L2-resident
            #pragma unroll
            for (int r = 0; r < R_ROWS; ++r) {
                float t1v = ui[r] * h.y;
                float zr = fmaf(ur[r], h.x, t1v);     // Re(conj(u)h)
                float t2v = ui[r] * h.x;
                float zi = fmaf(ur[r], h.y, -t2v);    // Im(conj(u)h)
                accm[r][j] = fmaf(ws[r],  zr, accm[r][j]);
                accx[r][j] = fmaf(wcr[r], zr, fmaf(wci[r], zi, accx[r][j]));
                if (j < T_PTS - 1) {                  // u *= v (skip dead last)
                    float nr = fmaf(ur[r], vr[r], -(ui[r] * vi[r]));
                    ui[r]    = fmaf(ur[r], vi[r],   ui[r] * vr[r]);
                    ur[r]    = nr;
                }
            }
        }
    }

    #pragma unroll
    for (int r = 0; r < R_ROWS; ++r) {
        float* op = out + (n0 + r) * M_COLS;
        #pragma unroll
        for (int j = 0; j < T_PTS; ++j)
            op[1 + m0 + j * M_STRIDE] = accm[r][j];    // m in [1,2048]
        #pragma unroll
        for (int j = 0; j < T_PTS; ++j)
            op[4095 - m0 - j * M_STRIDE] = accx[r][j]; // 4096-m in [2048,4095]
    }

    if (blockIdx.x == 0 && tid == 0) {                // column 0, direct
        #pragma unroll
        for (int r = 0; r < R_ROWS; ++r) {
            int n = n0 + r;
            float a = 0.0f;
            #pragma unroll
            for (int d = 0; d < RANK; ++d)
                a = fmaf(g_Tab2[n * RANK + d].x, g_Hft[d * M_COLS].x, a);
            out[n * M_COLS] = a;
        }
    }
}

extern "C" void kernel_launch(void* const* d_in, const int* in_sizes, int n_in,
                              void* d_out, int out_size, void* d_ws, size_t ws_size,
                              hipStream_t stream) {
    const float* W   = (const float*)d_in[0];   // [1024, 8]
    const float* H   = (const float*)d_in[1];   // [8, 4096]
    const float* tau = (const float*)d_in[2];   // [1024, 8]

    fft_fused<<<dim3(128), dim3(512), 0, stream>>>(H, W, tau);

    dim3 grid(M_COLS / 2 / (256 * T_PTS), N_ROWS / R_ROWS);  // (2, 512)
    shiftnmf_main<<<grid, dim3(256), 0, stream>>>((float*)d_out);
}

// Round 21
// 18.956 us; speedup vs baseline: 1.2872x; 1.0081x over previous
//
#include <hip/hip_runtime.h>
#include <math.h>

#define N_ROWS 1024
#define RANK   8
#define M_COLS 4096

#define R_ROWS   2      // n-rows per thread (vectorized as float2 lanes)
#define T_PTS    2      // direct points per thread in [1,2048], stride 1024
#define M_STRIDE 1024

typedef float f2 __attribute__((ext_vector_type(2)));   // packed fp32 pair

// Static device scratch (fully overwritten every call before read).
__device__ float2 g_Hft[RANK * M_COLS];    // full FFT of softplus(H), 256 KB
__device__ float4 g_Tab4[N_ROWS * RANK];   // {vr, vi, wcr, wci} per (n,d), 128 KB
__device__ float2 g_Tab2[N_ROWS * RANK];   // {ws, tau}          per (n,d),  64 KB

// fast softplus: 2 trans + ~4 VALU. exact for x>20; inputs are ~N(0,1).
__device__ __forceinline__ float softplus_f(float x) {
    float t = __expf(x);
    float r = 0.69314718056f * __log2f(1.0f + t);
    return (x > 20.0f) ? x : r;
}
// hw trig: v_sin/v_cos compute sin/cos(2*pi*x), x in revolutions.
__device__ __forceinline__ float sin_rev(float x) { return __builtin_amdgcn_sinf(x); }
__device__ __forceinline__ float cos_rev(float x) { return __builtin_amdgcn_cosf(x); }
__device__ __forceinline__ float fract_f(float x) { return __builtin_amdgcn_fractf(x); }

// ---------------------------------------------------------------------------
// Widened fused FFT (R18-proven, unchanged): 128 blocks x 512 threads,
// split-sum stages, blocks 0..15 fill Tab4/Tab2.
// ---------------------------------------------------------------------------
__global__ void fft_fused(const float* __restrict__ H,
                          const float* __restrict__ W,
                          const float* __restrict__ tau) {
    __shared__ float  sHs[M_COLS];        // 16 KB
    __shared__ float2 sY [4 * 64];        // stage-A combined, [m0j][k0], 2 KB
    __shared__ float2 sP [512];           // partials (A and B), 4 KB

    const int tid = threadIdx.x;          // 0..511
    const int b   = blockIdx.x;           // 0..127
    const int d   = b >> 4;
    const int m0b = (b & 15) << 2;

    if (b < 16) {                         // table side-job: 16 x 512 = 8192
        int t = b * 512 + tid;
        float w  = softplus_f(W[t]);
        float tv = tau[t];
        float rv = fract_f(tv * ((float)M_STRIDE / (float)M_COLS));  // tv/4
        float4 t4;
        t4.x = cos_rev(rv);               // step = e^{+i 2pi tau*1024/M}
        t4.y = sin_rev(rv);
        float rc = fract_f(-tv);          // e^{-2pi i tau}
        t4.z = w * cos_rev(rc);           // wcr
        t4.w = w * sin_rev(rc);           // wci
        g_Tab4[t] = t4;
        g_Tab2[t] = make_float2(w, tv);
    }

    const float4* Hrow4 = (const float4*)(H + d * M_COLS);
    #pragma unroll
    for (int p = 0; p < 2; ++p) {
        int i = p * 512 + tid;
        float4 h4 = Hrow4[i];
        sHs[i*4+0] = softplus_f(h4.x);
        sHs[i*4+1] = softplus_f(h4.y);
        sHs[i*4+2] = softplus_f(h4.z);
        sHs[i*4+3] = softplus_f(h4.w);
    }
    __syncthreads();

    {   // stage A partial: tid = half*256 + m0j*64 + k0
        int k0   = tid & 63;
        int m0j  = (tid >> 6) & 3;
        int half = tid >> 8;
        int m0   = m0b + m0j;
        float mrev = (float)m0 * (1.0f / 64.0f);
        float rr =  cos_rev(mrev);
        float ri = -sin_rev(mrev);        // rot = e^{-2pi i m0/64}
        float twr = ((half & m0) & 1) ? -1.0f : 1.0f;   // exact init
        float twi = 0.0f;
        float ar = 0.0f, ai = 0.0f;
        int base = half << 5;
        #pragma unroll
        for (int k = 0; k < 32; ++k) {
            float v = sHs[((base + k) << 6) + k0];
            ar = fmaf(v, twr, ar);
            ai = fmaf(v, twi, ai);
            float nr = fmaf(twr, rr, -(twi * ri));
            twi      = fmaf(twr, ri,   twi * rr);
            twr = nr;
        }
        sP[tid] = make_float2(ar, ai);
    }
    __syncthreads();
    if (tid < 256) {
        float2 a = sP[tid], c = sP[256 + tid];
        sY[tid] = make_float2(a.x + c.x, a.y + c.y);
    }
    __syncthreads();

    {   // stage B partial: tid = half*256 + m0j*64 + m1
        int m1   = tid & 63;
        int m0j  = (tid >> 6) & 3;
        int half = tid >> 8;
        int m    = (m1 << 6) + m0b + m0j;
        float mrev = (float)m * (1.0f / 4096.0f);
        float rr =  cos_rev(mrev);
        float ri = -sin_rev(mrev);        // rot = e^{-2pi i m/4096}
        float irev = (float)((m * (half << 5)) & 4095) * (1.0f / 4096.0f);
        float twr =  cos_rev(irev);
        float twi = -sin_rev(irev);
        float ar = 0.0f, ai = 0.0f;
        int base = half << 5;
        #pragma unroll
        for (int k = 0; k < 32; ++k) {
            float2 y = sY[(m0j << 6) + base + k];
            ar = fmaf(y.x, twr, fmaf(-y.y, twi, ar));
            ai = fmaf(y.x, twi, fmaf( y.y, twr, ai));
            float nr = fmaf(twr, rr, -(twi * ri));
            twi      = fmaf(twr, ri,   twi * rr);
            twr = nr;
        }
        sP[tid] = make_float2(ar, ai);
    }
    __syncthreads();
    if (tid < 256) {
        int m1 = tid & 63, m0j = tid >> 6;
        float2 a = sP[tid], c = sP[256 + tid];
        int m = (m1 << 6) + m0b + m0j;
        g_Hft[d * M_COLS + m] = make_float2(a.x + c.x, a.y + c.y);
    }
}

// ---------------------------------------------------------------------------
// Main (R18 math; inner loop vectorized over the two n-rows as float2 ->
// v_pk_fma_f32 packed fp32, halving VALU issue if the compiler wasn't
// already SLP-packing). Trig stays scalar (2 trans per (r,d)).
// For m = 1+m0+j*1024:  u = e^{+i 2pi tau m/M}
//   zr = ur*hr + ui*hi ; zi = ur*hi - ui*hr
//   Re V[n,m]      += ws * zr
//   Re V[n,4096-m] += wcr*zr + wci*zi      (Hermitian mirror)
// grid (4,512) = 2048 blocks = 8 waves/SIMD; est. ~45 VGPR.
// ---------------------------------------------------------------------------
__global__ void shiftnmf_main(float* __restrict__ out) {
    int tid = threadIdx.x;
    int m0  = blockIdx.x * 256 + tid;     // 0..1023 ; m_j = 1 + m0 + j*1024
    int n0  = blockIdx.y * R_ROWS;

    float fm0 = (float)(1 + m0) * (1.0f / (float)M_COLS);

    f2 accm[T_PTS], accx[T_PTS];          // lane k = row n0+k
    #pragma unroll
    for (int j = 0; j < T_PTS; ++j) { accm[j] = (f2)0.0f; accx[j] = (f2)0.0f; }

    #pragma unroll
    for (int d = 0; d < RANK; ++d) {
        f2 ur, ui, vr, vi, ws, wcr, wci;
        #pragma unroll
        for (int r = 0; r < R_ROWS; ++r) {
            int nd = (n0 + r) * RANK + d;
            float4 t4 = g_Tab4[nd];                   // block-uniform
            float2 t2 = g_Tab2[nd];
            vr[r]  = t4.x;  vi[r]  = t4.y;
            wcr[r] = t4.z;  wci[r] = t4.w;
            ws[r]  = t2.x;
            float r0 = fract_f(t2.y * fm0);           // only per-thread trig
            ur[r] = cos_rev(r0);                      // u = e^{+i 2pi tau m_0/M}
            ui[r] = sin_rev(r0);
        }

        const float2* hp = g_Hft + d * M_COLS + 1 + m0;
        #pragma unroll
        for (int j = 0; j < T_PTS; ++j) {
            float2 h = hp[j * M_STRIDE];              // coalesced, L2-resident
            f2 hx = {h.x, h.x};
            f2 hy = {h.y, h.y};
            f2 zr = ur * hx + ui * hy;                // Re(conj(u)h)  [pk fma]
            f2 zi = ur * hy - ui * hx;                // Im(conj(u)h)  [pk fma]
            accm[j] = accm[j] + ws * zr;              // [pk fma]
            accx[j] = accx[j] + wcr * zr + wci * zi;  // [pk fma x2]
            if (j < T_PTS - 1) {                      // u *= v (skip dead last)
                f2 nr = ur * vr - ui * vi;            // [pk fma]
                ui    = ur * vi + ui * vr;            // [pk fma]
                ur    = nr;
            }
        }
    }

    #pragma unroll
    for (int r = 0; r < R_ROWS; ++r) {
        float* op = out + (n0 + r) * M_COLS;
        #pragma unroll
        for (int j = 0; j < T_PTS; ++j)
            op[1 + m0 + j * M_STRIDE] = accm[j][r];    // m in [1,2048]
        #pragma unroll
        for (int j = 0; j < T_PTS; ++j)
            op[4095 - m0 - j * M_STRIDE] = accx[j][r]; // 4096-m in [2048,4095]
    }

    if (blockIdx.x == 0 && tid == 0) {                // column 0, direct
        #pragma unroll
        for (int r = 0; r < R_ROWS; ++r) {
            int n = n0 + r;
            float a = 0.0f;
            #pragma unroll
            for (int d = 0; d < RANK; ++d)
                a = fmaf(g_Tab2[n * RANK + d].x, g_Hft[d * M_COLS].x, a);
            out[n * M_COLS] = a;
        }
    }
}

extern "C" void kernel_launch(void* const* d_in, const int* in_sizes, int n_in,
                              void* d_out, int out_size, void* d_ws, size_t ws_size,
                              hipStream_t stream) {
    const float* W   = (const float*)d_in[0];   // [1024, 8]
    const float* H   = (const float*)d_in[1];   // [8, 4096]
    const float* tau = (const float*)d_in[2];   // [1024, 8]

    fft_fused<<<dim3(128), dim3(512), 0, stream>>>(H, W, tau);

    dim3 grid(M_COLS / 2 / (256 * T_PTS), N_ROWS / R_ROWS);  // (4, 512)
    shiftnmf_main<<<grid, dim3(256), 0, stream>>>((float*)d_out);
}

// Round 22
// 18.558 us; speedup vs baseline: 1.3148x; 1.0214x over previous
//
#include <hip/hip_runtime.h>
#include <math.h>

#define N_ROWS 1024
#define RANK   8
#define M_COLS 4096

#define R_ROWS   2      // n-rows per thread
#define T_PTS    2      // direct points per thread in [1,2048], stride 1024
#define M_STRIDE 1024

// Static device scratch (fully overwritten every call before read).
__device__ float2 g_Hft[RANK * M_COLS];    // full FFT of softplus(H), 256 KB
__device__ float4 g_Tab4[N_ROWS * RANK];   // {vr, vi, wcr, wci} per (n,d), 128 KB
__device__ float2 g_Tab2[N_ROWS * RANK];   // {ws, tau}          per (n,d),  64 KB

// fast softplus: 2 trans + ~4 VALU. exact for x>20; inputs are ~N(0,1).
__device__ __forceinline__ float softplus_f(float x) {
    float t = __expf(x);
    float r = 0.69314718056f * __log2f(1.0f + t);
    return (x > 20.0f) ? x : r;
}
// hw trig: v_sin/v_cos compute sin/cos(2*pi*x), x in revolutions.
// gfx950 hw handles |x| well beyond our +-3 range; no fract needed there.
__device__ __forceinline__ float sin_rev(float x) { return __builtin_amdgcn_sinf(x); }
__device__ __forceinline__ float cos_rev(float x) { return __builtin_amdgcn_cosf(x); }
__device__ __forceinline__ float fract_f(float x) { return __builtin_amdgcn_fractf(x); }

// ---------------------------------------------------------------------------
// Widened fused FFT (R18-proven, unchanged): 128 blocks x 512 threads,
// split-sum stages, blocks 0..15 fill Tab4/Tab2.
// ---------------------------------------------------------------------------
__global__ void fft_fused(const float* __restrict__ H,
                          const float* __restrict__ W,
                          const float* __restrict__ tau) {
    __shared__ float  sHs[M_COLS];        // 16 KB
    __shared__ float2 sY [4 * 64];        // stage-A combined, [m0j][k0], 2 KB
    __shared__ float2 sP [512];           // partials (A and B), 4 KB

    const int tid = threadIdx.x;          // 0..511
    const int b   = blockIdx.x;           // 0..127
    const int d   = b >> 4;
    const int m0b = (b & 15) << 2;

    if (b < 16) {                         // table side-job: 16 x 512 = 8192
        int t = b * 512 + tid;
        float w  = softplus_f(W[t]);
        float tv = tau[t];
        float rv = fract_f(tv * ((float)M_STRIDE / (float)M_COLS));  // tv/4
        float4 t4;
        t4.x = cos_rev(rv);               // step = e^{+i 2pi tau*1024/M}
        t4.y = sin_rev(rv);
        float rc = fract_f(-tv);          // e^{-2pi i tau}
        t4.z = w * cos_rev(rc);           // wcr
        t4.w = w * sin_rev(rc);           // wci
        g_Tab4[t] = t4;
        g_Tab2[t] = make_float2(w, tv);
    }

    const float4* Hrow4 = (const float4*)(H + d * M_COLS);
    #pragma unroll
    for (int p = 0; p < 2; ++p) {
        int i = p * 512 + tid;
        float4 h4 = Hrow4[i];
        sHs[i*4+0] = softplus_f(h4.x);
        sHs[i*4+1] = softplus_f(h4.y);
        sHs[i*4+2] = softplus_f(h4.z);
        sHs[i*4+3] = softplus_f(h4.w);
    }
    __syncthreads();

    {   // stage A partial: tid = half*256 + m0j*64 + k0
        int k0   = tid & 63;
        int m0j  = (tid >> 6) & 3;
        int half = tid >> 8;
        int m0   = m0b + m0j;
        float mrev = (float)m0 * (1.0f / 64.0f);
        float rr =  cos_rev(mrev);
        float ri = -sin_rev(mrev);        // rot = e^{-2pi i m0/64}
        float twr = ((half & m0) & 1) ? -1.0f : 1.0f;   // exact init
        float twi = 0.0f;
        float ar = 0.0f, ai = 0.0f;
        int base = half << 5;
        #pragma unroll
        for (int k = 0; k < 32; ++k) {
            float v = sHs[((base + k) << 6) + k0];
            ar = fmaf(v, twr, ar);
            ai = fmaf(v, twi, ai);
            float nr = fmaf(twr, rr, -(twi * ri));
            twi      = fmaf(twr, ri,   twi * rr);
            twr = nr;
        }
        sP[tid] = make_float2(ar, ai);
    }
    __syncthreads();
    if (tid < 256) {
        float2 a = sP[tid], c = sP[256 + tid];
        sY[tid] = make_float2(a.x + c.x, a.y + c.y);
    }
    __syncthreads();

    {   // stage B partial: tid = half*256 + m0j*64 + m1
        int m1   = tid & 63;
        int m0j  = (tid >> 6) & 3;
        int half = tid >> 8;
        int m    = (m1 << 6) + m0b + m0j;
        float mrev = (float)m * (1.0f / 4096.0f);
        float rr =  cos_rev(mrev);
        float ri = -sin_rev(mrev);        // rot = e^{-2pi i m/4096}
        float irev = (float)((m * (half << 5)) & 4095) * (1.0f / 4096.0f);
        float twr =  cos_rev(irev);
        float twi = -sin_rev(irev);
        float ar = 0.0f, ai = 0.0f;
        int base = half << 5;
        #pragma unroll
        for (int k = 0; k < 32; ++k) {
            float2 y = sY[(m0j << 6) + base + k];
            ar = fmaf(y.x, twr, fmaf(-y.y, twi, ar));
            ai = fmaf(y.x, twi, fmaf( y.y, twr, ai));
            float nr = fmaf(twr, rr, -(twi * ri));
            twi      = fmaf(twr, ri,   twi * rr);
            twr = nr;
        }
        sP[tid] = make_float2(ar, ai);
    }
    __syncthreads();
    if (tid < 256) {
        int m1 = tid & 63, m0j = tid >> 6;
        float2 a = sP[tid], c = sP[256 + tid];
        int m = (m1 << 6) + m0b + m0j;
        g_Hft[d * M_COLS + m] = make_float2(a.x + c.x, a.y + c.y);
    }
}

// ---------------------------------------------------------------------------
// Main (R18 scalar math; changes: __launch_bounds__(256,8) pins VGPR<=64 so
// the grid's 8 waves/SIMD actually materializes; fract dropped (hw sin/cos
// domain covers |x|<~3); rfl dropped (compiler scalarizes uniform loads).
// For m = 1+m0+j*1024:  u = e^{+i 2pi tau m/M}
//   zr = ur*hr + ui*hi ; zi = ur*hi - ui*hr
//   Re V[n,m]      += ws * zr
//   Re V[n,4096-m] += wcr*zr + wci*zi      (Hermitian mirror)
// grid (4,512) = 2048 blocks.
// ---------------------------------------------------------------------------
__global__ __launch_bounds__(256, 8)
void shiftnmf_main(float* __restrict__ out) {
    int tid = threadIdx.x;
    int m0  = blockIdx.x * 256 + tid;     // 0..1023 ; m_j = 1 + m0 + j*1024
    int n0  = blockIdx.y * R_ROWS;

    float fm0 = (float)(1 + m0) * (1.0f / (float)M_COLS);

    float accm[R_ROWS][T_PTS];            // direct outputs, m
    float accx[R_ROWS][T_PTS];            // mirror outputs, 4096-m
    #pragma unroll
    for (int r = 0; r < R_ROWS; ++r)
        #pragma unroll
        for (int j = 0; j < T_PTS; ++j) { accm[r][j] = 0.0f; accx[r][j] = 0.0f; }

    #pragma unroll
    for (int d = 0; d < RANK; ++d) {
        float ur[R_ROWS], ui[R_ROWS];                 // unit phasor (per-lane)
        float vr[R_ROWS], vi[R_ROWS];                 // step (uniform)
        float ws[R_ROWS], wcr[R_ROWS], wci[R_ROWS];   // weights (uniform)
        #pragma unroll
        for (int r = 0; r < R_ROWS; ++r) {
            int nd = (n0 + r) * RANK + d;
            float4 t4 = g_Tab4[nd];                   // block-uniform
            float2 t2 = g_Tab2[nd];
            vr[r]  = t4.x;  vi[r]  = t4.y;
            wcr[r] = t4.z;  wci[r] = t4.w;
            ws[r]  = t2.x;
            float r0 = t2.y * fm0;                    // |r0| < ~3: hw domain ok
            ur[r] = cos_rev(r0);                      // u = e^{+i 2pi tau m_0/M}
            ui[r] = sin_rev(r0);
        }

        const float2* hp = g_Hft + d * M_COLS + 1 + m0;
        #pragma unroll
        for (int j = 0; j < T_PTS; ++j) {
            float2 h = hp[j * M_STRIDE];              // coalesced, L2-resident
            #pragma unroll
            for (int r = 0; r < R_ROWS; ++r) {
                float t1v = ui[r] * h.y;
                float zr = fmaf(ur[r], h.x, t1v);     // Re(conj(u)h)
                float t2v = ui[r] * h.x;
                float zi = fmaf(ur[r], h.y, -t2v);    // Im(conj(u)h)
                accm[r][j] = fmaf(ws[r],  zr, accm[r][j]);
                accx[r][j] = fmaf(wcr[r], zr, fmaf(wci[r], zi, accx[r][j]));
                if (j < T_PTS - 1) {                  // u *= v (skip dead last)
                    float nr = fmaf(ur[r], vr[r], -(ui[r] * vi[r]));
                    ui[r]    = fmaf(ur[r], vi[r],   ui[r] * vr[r]);
                    ur[r]    = nr;
                }
            }
        }
    }

    #pragma unroll
    for (int r = 0; r < R_ROWS; ++r) {
        float* op = out + (n0 + r) * M_COLS;
        #pragma unroll
        for (int j = 0; j < T_PTS; ++j)
            op[1 + m0 + j * M_STRIDE] = accm[r][j];    // m in [1,2048]
        #pragma unroll
        for (int j = 0; j < T_PTS; ++j)
            op[4095 - m0 - j * M_STRIDE] = accx[r][j]; // 4096-m in [2048,4095]
    }

    if (blockIdx.x == 0 && tid == 0) {                // column 0, direct
        #pragma unroll
        for (int r = 0; r < R_ROWS; ++r) {
            int n = n0 + r;
            float a = 0.0f;
            #pragma unroll
            for (int d = 0; d < RANK; ++d)
                a = fmaf(g_Tab2[n * RANK + d].x, g_Hft[d * M_COLS].x, a);
            out[n * M_COLS] = a;
        }
    }
}

extern "C" void kernel_launch(void* const* d_in, const int* in_sizes, int n_in,
                              void* d_out, int out_size, void* d_ws, size_t ws_size,
                              hipStream_t stream) {
    const float* W   = (const float*)d_in[0];   // [1024, 8]
    const float* H   = (const float*)d_in[1];   // [8, 4096]
    const float* tau = (const float*)d_in[2];   // [1024, 8]

    fft_fused<<<dim3(128), dim3(512), 0, stream>>>(H, W, tau);

    dim3 grid(M_COLS / 2 / (256 * T_PTS), N_ROWS / R_ROWS);  // (4, 512)
    shiftnmf_main<<<grid, dim3(256), 0, stream>>>((float*)d_out);
}